// Round 7
// baseline (113314.258 us; speedup 1.0000x reference)
//
#include <hip/hip_runtime.h>
#include <hip/hip_bf16.h>
#include <math.h>

#define BB 256
#define TT 256
#define VV 33
#define HH 512
#define DD 256
#define KKEY 512
#define G4 2048
#define K1P 832    // [x(33) | a(256) | h1(512)] = 801, padded to 832
#define K2P 1280   // [hprev(512) | a(256) | hself(512)] = 1280

typedef unsigned short u16;
typedef unsigned int u32;
typedef __attribute__((ext_vector_type(8))) short short8;
typedef __attribute__((ext_vector_type(4))) float float4v;

__device__ inline float bf2f(u16 v) {
    union { u32 u; float f; } c; c.u = ((u32)v) << 16; return c.f;
}
__device__ inline u16 f2bf(float f) {
    __hip_bfloat16 h = __float2bfloat16(f);
    union { __hip_bfloat16 h; u16 u; } c; c.h = h; return c.u;
}
__device__ inline void split_bf(float v, u16& hi, u16& lo) {
    hi = f2bf(v);
    lo = f2bf(v - bf2f(hi));
}

// ---------------- weight prep: Wt[col][k], natural gate-major col order ----------------
__global__ void prep_v6(const float* __restrict__ W, const float* __restrict__ U,
                        u16* __restrict__ WtH, u16* __restrict__ WtL, int Kd, int mode) {
    long idx = (long)blockIdx.x * blockDim.x + threadIdx.x;
    if (idx >= (long)G4 * Kd) return;
    int col = (int)(idx / Kd);
    int k = (int)(idx % Kd);
    float v = 0.f;
    if (mode == 1) {
        if (k < 289)      v = W[(long)k * G4 + col];
        else if (k < 801) v = U[(long)(k - 289) * G4 + col];
    } else {
        if (k < 768)       v = W[(long)k * G4 + col];
        else               v = U[(long)(k - 768) * G4 + col];
    }
    u16 hi, lo; split_bf(v, hi, lo);
    WtH[idx] = hi; WtL[idx] = lo;
}

// ---------------- keys transpose: keysT[b][d][k] = keys[b][k][d] ----------------
__global__ void transp_v7(const float* __restrict__ keys, float* __restrict__ keysT) {
    __shared__ float tl[32][33];
    int b = blockIdx.z;
    int kt0 = blockIdx.x * 32, dt0 = blockIdx.y * 32;
    int lx = threadIdx.x, ly = threadIdx.y;  // 32 x 8
    const float* src = keys + ((long)b * KKEY + kt0) * DD + dt0;
    for (int i = ly; i < 32; i += 8)
        tl[i][lx] = src[(long)i * DD + lx];
    __syncthreads();
    float* dst = keysT + ((long)b * DD + dt0) * KKEY + kt0;
    for (int i = ly; i < 32; i += 8)
        dst[(long)i * KKEY + lx] = tl[lx][i];
}

// ---------------- pack xcat[b][k] (bf16 hi/lo) from fp32 sources ----------------
__global__ void pack_v6(const float* __restrict__ x, const float* __restrict__ a,
                        const float* __restrict__ hp, const float* __restrict__ hs,
                        u16* __restrict__ H, u16* __restrict__ L, int Kd, int t, int mode) {
    long idx = (long)blockIdx.x * blockDim.x + threadIdx.x;
    if (idx >= (long)BB * Kd) return;
    int b = (int)(idx / Kd);
    int k = (int)(idx % Kd);
    float v = 0.f;
    if (mode == 1) {
        if (k < 33)       v = x[((long)b * TT + t) * VV + k];
        else if (k < 289) v = a[b * DD + (k - 33)];
        else if (k < 801) v = hs[(long)b * HH + (k - 289)];
    } else {
        if (k < 512)       v = hp[(long)b * HH + k];
        else if (k < 768)  v = a[b * DD + (k - 512)];
        else               v = hs[(long)b * HH + (k - 768)];
    }
    u16 hi, lo; split_bf(v, hi, lo);
    H[idx] = hi; L[idx] = lo;
}

// ---------------- z-GEMM: tile 32(m) x 64(n), grid 256, register prefetch ----------------
// bf16x3: A*B ~= Ah*Bh + Ah*Bl + Al*Bh
__global__ __launch_bounds__(256) void zmfma_v7(
    const u16* __restrict__ aH, const u16* __restrict__ aL, int Kd,
    const u16* __restrict__ wH, const u16* __restrict__ wL,
    const float* __restrict__ bias, float* __restrict__ z)
{
    __shared__ u16 AldsH[32 * 40];
    __shared__ u16 AldsL[32 * 40];
    __shared__ u16 WldsH[64 * 40];
    __shared__ u16 WldsL[64 * 40];

    int tid = threadIdx.x;
    int mt = blockIdx.x >> 5;    // 0..7
    int nt = blockIdx.x & 31;    // 0..31
    int M0 = mt * 32, N0 = nt * 64;

    int wave = tid >> 6, lane = tid & 63;
    int lr = lane & 15, lg = lane >> 4;
    int m_half = wave & 1, n_half = wave >> 1;

    // staging assignment: thread tid owns 3 slots
    //   A slot: tid<128 -> AH row tid>>2; else AL row (tid&127)>>2; part tid&3
    //   WH slot: row tid>>2 (0..63), part tid&3
    //   WL slot: same indexing
    int arow = (tid & 127) >> 2, apart = tid & 3;
    const u16* aSrc = (tid < 128 ? aH : aL) + (long)(M0 + arow) * Kd + apart * 8;
    u16* aDst = (tid < 128 ? AldsH : AldsL) + arow * 40 + apart * 8;
    int wrow = tid >> 2, wpart = tid & 3;
    const u16* whSrc = wH + (long)(N0 + wrow) * Kd + wpart * 8;
    const u16* wlSrc = wL + (long)(N0 + wrow) * Kd + wpart * 8;
    u16* whDst = WldsH + wrow * 40 + wpart * 8;
    u16* wlDst = WldsL + wrow * 40 + wpart * 8;

    float4v acc0 = {0.f,0.f,0.f,0.f}, acc1 = {0.f,0.f,0.f,0.f};

    uint4 ra = *(const uint4*)aSrc;
    uint4 rwh = *(const uint4*)whSrc;
    uint4 rwl = *(const uint4*)wlSrc;

    for (int k0 = 0; k0 < Kd; k0 += 32) {
        __syncthreads();
        *(uint4*)aDst = ra;
        *(uint4*)whDst = rwh;
        *(uint4*)wlDst = rwl;
        __syncthreads();
        if (k0 + 32 < Kd) {
            ra = *(const uint4*)(aSrc + k0 + 32);
            rwh = *(const uint4*)(whSrc + k0 + 32);
            rwl = *(const uint4*)(wlSrc + k0 + 32);
        }
        // A fragment: m = m_half*16 + (lane&15), k = (lane>>4)*8 + j
        short8 ah = *(const short8*)(&AldsH[(m_half * 16 + lr) * 40 + lg * 8]);
        short8 al = *(const short8*)(&AldsL[(m_half * 16 + lr) * 40 + lg * 8]);
        // B^T fragments: n = n_half*32 + tt*16 + (lane&15)
        short8 bh0 = *(const short8*)(&WldsH[(n_half * 32 + lr) * 40 + lg * 8]);
        short8 bl0 = *(const short8*)(&WldsL[(n_half * 32 + lr) * 40 + lg * 8]);
        short8 bh1 = *(const short8*)(&WldsH[(n_half * 32 + 16 + lr) * 40 + lg * 8]);
        short8 bl1 = *(const short8*)(&WldsL[(n_half * 32 + 16 + lr) * 40 + lg * 8]);
        acc0 = __builtin_amdgcn_mfma_f32_16x16x32_bf16(ah, bh0, acc0, 0, 0, 0);
        acc0 = __builtin_amdgcn_mfma_f32_16x16x32_bf16(ah, bl0, acc0, 0, 0, 0);
        acc0 = __builtin_amdgcn_mfma_f32_16x16x32_bf16(al, bh0, acc0, 0, 0, 0);
        acc1 = __builtin_amdgcn_mfma_f32_16x16x32_bf16(ah, bh1, acc1, 0, 0, 0);
        acc1 = __builtin_amdgcn_mfma_f32_16x16x32_bf16(ah, bl1, acc1, 0, 0, 0);
        acc1 = __builtin_amdgcn_mfma_f32_16x16x32_bf16(al, bh1, acc1, 0, 0, 0);
    }

    // D: col = lane&15 within 16-block, row m = (lane>>4)*4 + r   [m89-verified]
    int m_base = M0 + m_half * 16 + lg * 4;
    {
        int col = N0 + n_half * 32 + lr;
        float bv = bias[col];
        #pragma unroll
        for (int r = 0; r < 4; r++)
            z[(long)(m_base + r) * G4 + col] = acc0[r] + bv;
    }
    {
        int col = N0 + n_half * 32 + 16 + lr;
        float bv = bias[col];
        #pragma unroll
        for (int r = 0; r < 4; r++)
            z[(long)(m_base + r) * G4 + col] = acc1[r] + bv;
    }
}

// ---------------- fused cell: gates -> q -> attention (one block per sample) ----------------
__global__ __launch_bounds__(512) void cell_v7(
    const float* __restrict__ z, float* __restrict__ c, float* __restrict__ h,
    const float* __restrict__ Wq, const float* __restrict__ bq,
    const float* __restrict__ keys, const float* __restrict__ keysT, int use_kt,
    float* __restrict__ a_out)
{
    __shared__ float hl[HH];
    __shared__ float ql[DD];
    __shared__ float pl[KKEY];
    __shared__ float qpar[2][DD];
    __shared__ float red[16];

    int b = blockIdx.x, tid = threadIdx.x;
    int lane = tid & 63, wave = tid >> 6;

    // ---- gates: thread = unit u ----
    {
        const float* zrow = z + (long)b * G4;
        float zi = zrow[tid];
        float zf = zrow[512 + tid];
        float zg = zrow[1024 + tid];
        float zo = zrow[1536 + tid];
        float i_ = 1.f / (1.f + expf(-zi));
        float f_ = 1.f / (1.f + expf(-zf));
        float g_ = tanhf(zg);
        float o_ = 1.f / (1.f + expf(-zo));
        long ci = (long)b * HH + tid;
        float cn = f_ * c[ci] + i_ * g_;
        c[ci] = cn;
        float hn = o_ * tanhf(cn);
        h[ci] = hn;
        hl[tid] = hn;
    }
    __syncthreads();

    // ---- q = hl @ Wq + bq : d = tid&255, half-split over j ----
    {
        int d = tid & 255, half = tid >> 8;
        float s = 0.f;
        int j0 = half * 256;
        for (int j = j0; j < j0 + 256; j++)
            s += hl[j] * Wq[(long)j * DD + d];
        qpar[half][d] = s;
    }
    __syncthreads();
    if (tid < DD) ql[tid] = bq[tid] + qpar[0][tid] + qpar[1][tid];
    __syncthreads();

    // ---- scores: thread = key k ----
    float s = 0.f;
    if (use_kt) {
        const float* kt = keysT + (long)b * DD * KKEY + tid;
        for (int d = 0; d < DD; d++)
            s += kt[(long)d * KKEY] * ql[d];
    } else {
        const float* kb = keys + ((long)b * KKEY + tid) * DD;
        for (int d = 0; d < DD; d++)
            s += kb[d] * ql[d];
    }
    // ---- softmax over 512 threads ----
    float m = s;
    for (int o = 32; o > 0; o >>= 1) m = fmaxf(m, __shfl_xor(m, o));
    if (lane == 0) red[wave] = m;
    __syncthreads();
    m = red[0];
    #pragma unroll
    for (int w = 1; w < 8; w++) m = fmaxf(m, red[w]);
    float pv = expf(s - m);
    pl[tid] = pv;
    float ps = pv;
    for (int o = 32; o > 0; o >>= 1) ps += __shfl_xor(ps, o);
    if (lane == 0) red[8 + wave] = ps;
    __syncthreads();
    float l = red[8];
    #pragma unroll
    for (int w = 9; w < 16; w++) l += red[w];

    // ---- weighted read: d = tid&255, half-split over k ----
    {
        int d = tid & 255, half = tid >> 8;
        float acc = 0.f;
        int k0 = half * 256;
        const float* kcol = keys + ((long)b * KKEY + k0) * DD + d;
        for (int kk = 0; kk < 256; kk++)
            acc += pl[k0 + kk] * kcol[(long)kk * DD];
        qpar[half][d] = acc;
    }
    __syncthreads();
    if (tid < DD) a_out[(long)b * DD + tid] = (qpar[0][tid] + qpar[1][tid]) / l;
}

// ---------------- out[:, t, :] = concat(h3, a3) @ Wo + bo ----------------
__global__ __launch_bounds__(64) void out_naive(
    const float* __restrict__ h3, const float* __restrict__ a3,
    const float* __restrict__ Wo, const float* __restrict__ bo,
    float* __restrict__ out, int t)
{
    int b = blockIdx.x, v = threadIdx.x;
    if (v >= VV) return;
    float s = bo[v];
    for (int i = 0; i < HH; i++)
        s += h3[(long)b * HH + i] * Wo[(long)i * VV + v];
    for (int i = 0; i < DD; i++)
        s += a3[b * DD + i] * Wo[(long)(HH + i) * VV + v];
    out[((long)b * TT + t) * VV + v] = s;
}

// ---------------- launch ----------------

extern "C" void kernel_launch(void* const* d_in, const int* in_sizes, int n_in,
                              void* d_out, int out_size, void* d_ws, size_t ws_size,
                              hipStream_t stream) {
    const float *x = nullptr, *keys = nullptr, *W1 = nullptr, *U1 = nullptr,
                *b1 = nullptr, *W2 = nullptr, *U2 = nullptr, *b2 = nullptr,
                *W3 = nullptr, *U3 = nullptr, *b3 = nullptr, *Wq = nullptr,
                *bq = nullptr, *Wo = nullptr, *bo = nullptr;
    {
        int cW23 = 0, cU = 0, cb = 0;
        for (int i = 0; i < n_in; i++) {
            const float* q = (const float*)d_in[i];
            switch (in_sizes[i]) {
                case 2162688:  x = q; break;
                case 33554432: keys = q; break;
                case 591872:   W1 = q; break;
                case 1572864:  if (cW23 == 0) W2 = q; else W3 = q; cW23++; break;
                case 1048576:  if (cU == 0) U1 = q; else if (cU == 1) U2 = q; else U3 = q; cU++; break;
                case 2048:     if (cb == 0) b1 = q; else if (cb == 1) b2 = q; else b3 = q; cb++; break;
                case 131072:   Wq = q; break;
                case 256:      bq = q; break;
                case 25344:    Wo = q; break;
                case 33:       bo = q; break;
                default: break;
            }
        }
    }
    float* out = (float*)d_out;

    char* p = (char*)d_ws;
    auto alloc = [&](size_t n) { char* r = p; p += (n + 255) & ~(size_t)255; return r; };
    u16* WtH1 = (u16*)alloc((size_t)G4 * K1P * 2);
    u16* WtL1 = (u16*)alloc((size_t)G4 * K1P * 2);
    u16* WtH2 = (u16*)alloc((size_t)G4 * K2P * 2);
    u16* WtL2 = (u16*)alloc((size_t)G4 * K2P * 2);
    u16* WtH3 = (u16*)alloc((size_t)G4 * K2P * 2);
    u16* WtL3 = (u16*)alloc((size_t)G4 * K2P * 2);
    u16* xcH1 = (u16*)alloc((size_t)BB * K1P * 2);
    u16* xcL1 = (u16*)alloc((size_t)BB * K1P * 2);
    u16* xcH2 = (u16*)alloc((size_t)BB * K2P * 2);
    u16* xcL2 = (u16*)alloc((size_t)BB * K2P * 2);
    u16* xcH3 = (u16*)alloc((size_t)BB * K2P * 2);
    u16* xcL3 = (u16*)alloc((size_t)BB * K2P * 2);
    float* h1 = (float*)alloc((size_t)BB * HH * 4);
    float* c1 = (float*)alloc((size_t)BB * HH * 4);
    float* h2 = (float*)alloc((size_t)BB * HH * 4);
    float* c2 = (float*)alloc((size_t)BB * HH * 4);
    float* h3 = (float*)alloc((size_t)BB * HH * 4);
    float* c3 = (float*)alloc((size_t)BB * HH * 4);
    float* a  = (float*)alloc((size_t)BB * DD * 4);
    float* at = (float*)alloc((size_t)BB * DD * 4);
    float* zb = (float*)alloc((size_t)BB * G4 * 4);
    // keysT allocated LAST so fallback doesn't disturb other pointers
    size_t used_before_kt = (size_t)(p - (char*)d_ws);
    size_t kt_bytes = (size_t)BB * KKEY * DD * 4;
    int use_kt = (used_before_kt + kt_bytes <= ws_size) ? 1 : 0;
    float* keysT = use_kt ? (float*)alloc(kt_bytes) : nullptr;

    // prep
    {
        long t1 = (long)G4 * K1P;
        prep_v6<<<(int)((t1 + 255) / 256), 256, 0, stream>>>(W1, U1, WtH1, WtL1, K1P, 1);
        long t2 = (long)G4 * K2P;
        prep_v6<<<(int)((t2 + 255) / 256), 256, 0, stream>>>(W2, U2, WtH2, WtL2, K2P, 2);
        prep_v6<<<(int)((t2 + 255) / 256), 256, 0, stream>>>(W3, U3, WtH3, WtL3, K2P, 2);
        if (use_kt)
            transp_v7<<<dim3(KKEY / 32, DD / 32, BB), dim3(32, 8), 0, stream>>>(keys, keysT);
        hipMemsetAsync(h1, 0, (size_t)BB * HH * 4, stream);
        hipMemsetAsync(c1, 0, (size_t)BB * HH * 4, stream);
        hipMemsetAsync(h2, 0, (size_t)BB * HH * 4, stream);
        hipMemsetAsync(c2, 0, (size_t)BB * HH * 4, stream);
        hipMemsetAsync(h3, 0, (size_t)BB * HH * 4, stream);
        hipMemsetAsync(c3, 0, (size_t)BB * HH * 4, stream);
        hipMemsetAsync(a,  0, (size_t)BB * DD * 4, stream);
    }

    int g1 = (BB * K1P + 255) / 256;
    int g2 = (BB * K2P + 255) / 256;

    for (int t = 0; t < TT; t++) {
        // LSTM1: xcat = [x_t | a | h1]
        pack_v6<<<g1, 256, 0, stream>>>(x, a, nullptr, h1, xcH1, xcL1, K1P, t, 1);
        zmfma_v7<<<256, 256, 0, stream>>>(xcH1, xcL1, K1P, WtH1, WtL1, b1, zb);
        cell_v7<<<BB, 512, 0, stream>>>(zb, c1, h1, Wq, bq, keys, keysT, use_kt, at);   // a1
        // LSTM2: xcat = [h1 | a1 | h2]
        pack_v6<<<g2, 256, 0, stream>>>(nullptr, at, h1, h2, xcH2, xcL2, K2P, t, 2);
        zmfma_v7<<<256, 256, 0, stream>>>(xcH2, xcL2, K2P, WtH2, WtL2, b2, zb);
        cell_v7<<<BB, 512, 0, stream>>>(zb, c2, h2, Wq, bq, keys, keysT, use_kt, at);   // a2
        // LSTM3: xcat = [h2 | a2 | h3]
        pack_v6<<<g2, 256, 0, stream>>>(nullptr, at, h2, h3, xcH3, xcL3, K2P, t, 2);
        zmfma_v7<<<256, 256, 0, stream>>>(xcH3, xcL3, K2P, WtH3, WtL3, b3, zb);
        cell_v7<<<BB, 512, 0, stream>>>(zb, c3, h3, Wq, bq, keys, keysT, use_kt, a);    // a3 carry
        // out
        out_naive<<<BB, 64, 0, stream>>>(h3, a, Wo, bo, out, t);
    }
}